// Round 10
// baseline (283.452 us; speedup 1.0000x reference)
//
#include <hip/hip_runtime.h>
#include <hip/hip_bf16.h>

// B=2 S=2048 HID=1024 NH=16 HD=64 SKV=2048 L=4096
// d_in: 0 hidden, 1 kvs, 2 Wq, 3 bq, 4 Wk, 5 bk, 6 Wv, 7 bv, 8 kv_weight

typedef __bf16 bf16x8 __attribute__((ext_vector_type(8)));
typedef float f32x4 __attribute__((ext_vector_type(4)));
typedef float f32x16 __attribute__((ext_vector_type(16)));
typedef unsigned int uint4v __attribute__((ext_vector_type(4)));
typedef unsigned short u16x4 __attribute__((ext_vector_type(4)));

#define QSCALE 0.0225421100138900525f  // (1/64) * log2(e): folds both HD^-0.5 scales + exp->exp2

static __device__ __forceinline__ unsigned short bf16b(float f) {
  return __builtin_bit_cast(unsigned short, __float2bfloat16(f));
}
static __device__ __forceinline__ unsigned pk2(float lo, float hi) {
  return (unsigned)bf16b(lo) | ((unsigned)bf16b(hi) << 16);
}
static __device__ __forceinline__ bf16x8 ld16s(const unsigned short* p) {
  return __builtin_bit_cast(bf16x8, *(const uint4v*)p);
}
static __device__ __forceinline__ float fexp2(float x) {
  float r; asm("v_exp_f32 %0, %1" : "=v"(r) : "v"(x)); return r;
}

typedef __attribute__((address_space(1))) const void gas_void;
typedef __attribute__((address_space(3))) void las_void;
static __device__ __forceinline__ void gload_lds16(const void* g, void* l) {
  __builtin_amdgcn_global_load_lds((gas_void*)g, (las_void*)l, 16, 0, 0);
}

// ---------------- prep: f32->bf16 conversions + kvs[0] -> K buffer ----------------
__global__ __launch_bounds__(256) void prep_convert(
    const float* __restrict__ hs, const float* __restrict__ wq,
    const float* __restrict__ wk, const float* __restrict__ wv,
    const float* __restrict__ kv0, const float* __restrict__ kvw,
    unsigned short* __restrict__ hsb, unsigned short* __restrict__ wb,
    unsigned short* __restrict__ kbuf) {
  long i = ((long)blockIdx.x * 256 + threadIdx.x) * 4;
  const float* src; unsigned short* dst; float s = 1.0f;
  if (i < 4194304)      { src = hs + i;           dst = hsb + i; }
  else if (i < 5242880) { src = wq + (i-4194304); dst = wb + (i-4194304); }
  else if (i < 6291456) { src = wk + (i-5242880); dst = wb + 1048576 + (i-5242880); }
  else if (i < 7340032) { src = wv + (i-6291456); dst = wb + 2097152 + (i-6291456); }
  else { long j = i - 7340032; s = *kvw;
         long bh = j >> 17, r = j & 131071;           // kvs[0]: [bh][2048][64] -> K rows 0..2047 of [bh][4096][64]
         src = kv0 + j; dst = kbuf + (bh << 18) + r; }
  float4 v = *(const float4*)src;
  u16x4 o = { bf16b(v.x*s), bf16b(v.y*s), bf16b(v.z*s), bf16b(v.w*s) };
  *(u16x4*)dst = o;
}

// ---------------- fused QKV projection GEMM (128x128 tile, BK=32, 4 waves) ----------------
// A = hidden bf16 [4096][1024]; W row-major [out][in] == B^T; y = x@W.T + b
// mode 2 (V) writes V^T [bh][64][4096] directly (cols 2048+s) -- no separate transpose pass.
__global__ __launch_bounds__(256) void qkv_gemm(
    const unsigned short* __restrict__ A, const unsigned short* __restrict__ W,
    const float* __restrict__ bq, const float* __restrict__ bk, const float* __restrict__ bv,
    unsigned short* __restrict__ qb, unsigned short* __restrict__ kbuf,
    unsigned short* __restrict__ vtb) {
  int mode = blockIdx.y;
  const unsigned short* Wm = W + mode * 1048576;
  const float* bias = (mode == 0) ? bq : ((mode == 1) ? bk : bv);
  int mt = blockIdx.x >> 3, nt = blockIdx.x & 7;
  int m0 = mt << 7, n0 = nt << 7;
  int wid = threadIdx.x >> 6, ln = threadIdx.x & 63;
  int wr = wid >> 1, wc = wid & 1;
  __shared__ unsigned short As[2][4096], Bs[2][4096];

  f32x4 acc[4][4] = {};

  auto stage = [&](int bb, int kt) {
    #pragma unroll
    for (int i = 0; i < 2; ++i) {
      int c = i*256 + wid*64 + ln;   // chunk16 id 0..511
      int row = c >> 2, sl = c & 3;  // 128 rows x 4 x 16B
      int lb = (i*256 + wid*64) * 8; // wave-uniform LDS base (elems)
      gload_lds16(A  + (long)(m0 + row)*1024 + kt*32 + sl*8, &As[bb][lb]);
      gload_lds16(Wm + (long)(n0 + row)*1024 + kt*32 + sl*8, &Bs[bb][lb]);
    }
  };

  stage(0, 0);
  __syncthreads();
  int buf = 0;
  for (int kt = 0; kt < 32; ++kt) {
    if (kt < 31) stage(buf ^ 1, kt + 1);
    bf16x8 a[4], b[4];
    int rsel = (ln & 15), ksel = (ln >> 4) * 8;
    #pragma unroll
    for (int x = 0; x < 4; ++x) {
      a[x] = ld16s(&As[buf][(wr*64 + x*16 + rsel)*32 + ksel]);
      b[x] = ld16s(&Bs[buf][(wc*64 + x*16 + rsel)*32 + ksel]);
    }
    __builtin_amdgcn_s_setprio(1);
    #pragma unroll
    for (int x = 0; x < 4; ++x)
      #pragma unroll
      for (int y = 0; y < 4; ++y)
        acc[x][y] = __builtin_amdgcn_mfma_f32_16x16x32_bf16(a[x], b[y], acc[x][y], 0, 0, 0);
    __builtin_amdgcn_s_setprio(0);
    __syncthreads();
    buf ^= 1;
  }

  float bias4[4];
  #pragma unroll
  for (int y = 0; y < 4; ++y) bias4[y] = bias[n0 + wc*64 + y*16 + (ln & 15)];

  if (mode == 2) {
    // write V^T: 4 consecutive s at fixed (bh, d) -> contiguous 8B
    #pragma unroll
    for (int x = 0; x < 4; ++x)
      #pragma unroll
      for (int y = 0; y < 4; ++y) {
        int gm = m0 + wr*64 + x*16 + (ln >> 4)*4;       // s-run start (4 consecutive)
        int gn = n0 + wc*64 + y*16 + (ln & 15);
        int bb = gm >> 11, s = gm & 2047, h = gn >> 6, d = gn & 63;
        long bh = bb*16 + h;
        u16x4 o = { bf16b(acc[x][y][0] + bias4[y]), bf16b(acc[x][y][1] + bias4[y]),
                    bf16b(acc[x][y][2] + bias4[y]), bf16b(acc[x][y][3] + bias4[y]) };
        *(u16x4*)(vtb + bh*262144 + (long)d*4096 + 2048 + s) = o;
      }
  } else {
    #pragma unroll
    for (int x = 0; x < 4; ++x)
      #pragma unroll
      for (int y = 0; y < 4; ++y)
        #pragma unroll
        for (int r = 0; r < 4; ++r) {
          int gm = m0 + wr*64 + x*16 + (ln >> 4)*4 + r;   // C/D: col=l&15, row=(l>>4)*4+r
          int gn = n0 + wc*64 + y*16 + (ln & 15);
          float v = acc[x][y][r] + bias4[y];
          int bb = gm >> 11, s = gm & 2047, h = gn >> 6, d = gn & 63;
          long bh = bb*16 + h;
          if (mode == 0) qb[(bh*2048 + s)*64 + d]          = bf16b(v * QSCALE);
          else           kbuf[(bh*4096 + 2048 + s)*64 + d] = bf16b(v);
        }
  }
}

// ---------------- transpose kvs[1] f32 [bh][s][64] -> V^T [bh][64][4096] cols 0..2047 ----------------
__global__ __launch_bounds__(256) void transpose_v(
    const float* __restrict__ src, unsigned short* __restrict__ dst,
    const float* __restrict__ scale_ptr) {
  __shared__ float tile[64 * 65];
  int bh = blockIdx.x >> 5;
  int s0 = (blockIdx.x & 31) << 6;
  int tid = threadIdx.x;
  float sc = *scale_ptr;
  long sb = ((long)bh*2048 + s0) * 64;
  #pragma unroll
  for (int j = 0; j < 4; ++j) {
    int c = tid + j*256;
    int row = c >> 4, sl = c & 15;
    float4 v = *(const float4*)(src + sb + row*64 + sl*4);
    float* p = &tile[row*65 + sl*4];
    p[0] = v.x*sc; p[1] = v.y*sc; p[2] = v.z*sc; p[3] = v.w*sc;
  }
  __syncthreads();
  int d = tid >> 2, kc = tid & 3;
  unsigned short u16[16];
  #pragma unroll
  for (int t = 0; t < 16; ++t) u16[t] = bf16b(tile[(kc*16 + t)*65 + d]);
  uint4v o0v = { (unsigned)u16[0] | ((unsigned)u16[1]<<16), (unsigned)u16[2] | ((unsigned)u16[3]<<16),
                 (unsigned)u16[4] | ((unsigned)u16[5]<<16), (unsigned)u16[6] | ((unsigned)u16[7]<<16) };
  uint4v o1v = { (unsigned)u16[8] | ((unsigned)u16[9]<<16), (unsigned)u16[10] | ((unsigned)u16[11]<<16),
                 (unsigned)u16[12] | ((unsigned)u16[13]<<16), (unsigned)u16[14] | ((unsigned)u16[15]<<16) };
  long db = (long)bh*262144 + (long)d*4096 + s0 + kc*16;
  *(uint4v*)(dst + db) = o0v;
  *(uint4v*)(dst + db + 8) = o1v;
}

// ---------------- flash attention: L2-direct K/V reads, NO LDS, NO barriers ----------------
// Per-head K+V^T = 512 KB << 4 MB XCD L2, so staging to LDS was pure overhead
// (barrier lockstep + ds_read issue + bank conflicts). Each wave streams K/V
// fragments straight from L2; loads pipeline under its own MFMAs.
// No max tracking: Q pre-scaled so |scores| << 20; exp2 direct is exact-safe in f32.
template <int NT, bool DIRECT>
__global__ __launch_bounds__(256) void attn(
    const unsigned short* __restrict__ qb, const unsigned short* __restrict__ kb,
    const unsigned short* __restrict__ vtb, float* __restrict__ out,
    float* __restrict__ po, float* __restrict__ pl) {
  int tilei = blockIdx.x, bh = blockIdx.y, sp = blockIdx.z;
  int keyoff = sp * NT * 64;
  int wid = threadIdx.x >> 6, ln = threadIdx.x & 63;
  int lo = ln & 31, hi = ln >> 5;

  const unsigned short* kg = kb  + (long)bh * 262144;
  const unsigned short* vg = vtb + (long)bh * 262144;
  int qbase = tilei*256 + wid*64;
  bf16x8 qf[2][4];
  #pragma unroll
  for (int g = 0; g < 2; ++g) {
    const unsigned short* qrow = qb + ((long)bh*2048 + qbase + g*32 + lo) * 64;
    #pragma unroll
    for (int ds = 0; ds < 4; ++ds) qf[g][ds] = ld16s(qrow + ds*16 + hi*8); // B-frag: col=q, k=8*hi+j
  }

  f32x16 o[2][2] = {};   // [group][dh]
  f32x4 lacc[2] = {};

  const unsigned short* krow = kg + (long)(keyoff + lo)*64 + hi*8;        // lane's K row, k-half hi
  const unsigned short* vrow0 = vg + (long)lo*4096 + keyoff + hi*8;       // lane's V^T row (d=lo)
  const unsigned short* vrow1 = vg + (long)(32+lo)*4096 + keyoff + hi*8;  // d=32+lo

  for (int t = 0; t < NT; ++t) {
    #pragma unroll
    for (int cc = 0; cc < 2; ++cc) {
      // S^T = K . Q^T : lane owns query (qbase+g*32+lo), keys (r&3)+8*(r>>2)+4*hi
      long kbase = (long)(t*64 + cc*32) * 64;
      bf16x8 kf[4];
      #pragma unroll
      for (int ds = 0; ds < 4; ++ds)
        kf[ds] = ld16s(krow + kbase + ds*16);
      bf16x8 pf[2][2];
      #pragma unroll
      for (int g = 0; g < 2; ++g) {
        f32x16 st = {};
        __builtin_amdgcn_s_setprio(1);
        #pragma unroll
        for (int ds = 0; ds < 4; ++ds)
          st = __builtin_amdgcn_mfma_f32_32x32x16_bf16(kf[ds], qf[g][ds], st, 0, 0, 0);
        __builtin_amdgcn_s_setprio(0);
        float p[16];
        #pragma unroll
        for (int r = 0; r < 16; ++r) p[r] = fexp2(st[r]);
        f32x4 l4 = { (p[0]+p[1]) + (p[2]+p[3]),   (p[4]+p[5]) + (p[6]+p[7]),
                     (p[8]+p[9]) + (p[10]+p[11]), (p[12]+p[13]) + (p[14]+p[15]) };
        lacc[g] += l4;
        // P^T B-frags via cvt_pk + permlane32_swap (T12)
        #pragma unroll
        for (int ks = 0; ks < 2; ++ks) {
          unsigned X  = pk2(p[8*ks+0], p[8*ks+1]);
          unsigned X2 = pk2(p[8*ks+2], p[8*ks+3]);
          unsigned Y  = pk2(p[8*ks+4], p[8*ks+5]);
          unsigned Y2 = pk2(p[8*ks+6], p[8*ks+7]);
          asm("v_permlane32_swap_b32 %0, %1" : "+v"(X), "+v"(Y));
          asm("v_permlane32_swap_b32 %0, %1" : "+v"(X2), "+v"(Y2));
          uint4v pw = { X, X2, Y, Y2 };
          pf[g][ks] = __builtin_bit_cast(bf16x8, pw);
        }
      }
      // O^T += V^T . P^T — V-frags shared by both query groups
      #pragma unroll
      for (int ks = 0; ks < 2; ++ks) {
        int vcol = t*64 + cc*32 + ks*16;
        bf16x8 vf0 = ld16s(vrow0 + vcol);
        bf16x8 vf1 = ld16s(vrow1 + vcol);
        __builtin_amdgcn_s_setprio(1);
        #pragma unroll
        for (int g = 0; g < 2; ++g) {
          o[g][0] = __builtin_amdgcn_mfma_f32_32x32x16_bf16(vf0, pf[g][ks], o[g][0], 0, 0, 0);
          o[g][1] = __builtin_amdgcn_mfma_f32_32x32x16_bf16(vf1, pf[g][ks], o[g][1], 0, 0, 0);
        }
        __builtin_amdgcn_s_setprio(0);
      }
    }
  }

  #pragma unroll
  for (int g = 0; g < 2; ++g) {
    float lsum = (lacc[g][0] + lacc[g][1]) + (lacc[g][2] + lacc[g][3]);
    lsum += __shfl_xor(lsum, 32, 64);
    int q = qbase + g*32 + lo;
    if constexpr (DIRECT) {
      float inv = 1.0f / lsum;
      int bb = bh >> 4, h = bh & 15;
      float* orow = out + ((long)bb*2048 + q)*1024 + h*64;
      #pragma unroll
      for (int dh = 0; dh < 2; ++dh) {
        #pragma unroll
        for (int gg = 0; gg < 4; ++gg) {
          f32x4 vv = { o[g][dh][4*gg]*inv, o[g][dh][4*gg+1]*inv,
                       o[g][dh][4*gg+2]*inv, o[g][dh][4*gg+3]*inv };
          *(f32x4*)(orow + dh*32 + gg*8 + 4*hi) = vv;   // d = (r&3)+8*(r>>2)+4*hi (+32*dh)
        }
      }
    } else {
      float* prow = po + (((long)sp*32 + bh)*2048 + q) * 64;
      #pragma unroll
      for (int dh = 0; dh < 2; ++dh) {
        #pragma unroll
        for (int gg = 0; gg < 4; ++gg) {
          f32x4 vv = { o[g][dh][4*gg], o[g][dh][4*gg+1], o[g][dh][4*gg+2], o[g][dh][4*gg+3] };
          *(f32x4*)(prow + dh*32 + gg*8 + 4*hi) = vv;
        }
      }
      if (hi == 0) pl[((long)sp*32 + bh)*2048 + q] = lsum;
    }
  }
}

// ---------------- combine 2 key-split partials: out = (O0+O1)/(l0+l1) ----------------
__global__ __launch_bounds__(256) void combine2(
    const float* __restrict__ po, const float* __restrict__ pl, float* __restrict__ out) {
  long flat = ((long)blockIdx.x * 256 + threadIdx.x) * 4;   // over 32*2048*64
  int bh = (int)(flat >> 17);
  int rem = (int)(flat & 131071);
  int q = rem >> 6, d = rem & 63;
  f32x4 a = *(const f32x4*)(po + flat);
  f32x4 b = *(const f32x4*)(po + 4194304 + flat);
  float l = pl[bh*2048 + q] + pl[65536 + bh*2048 + q];
  float inv = 1.0f / l;
  f32x4 r = { (a[0]+b[0])*inv, (a[1]+b[1])*inv, (a[2]+b[2])*inv, (a[3]+b[3])*inv };
  *(f32x4*)(out + ((long)(bh >> 4)*2048 + q)*1024 + (bh & 15)*64 + d) = r;
}

extern "C" void kernel_launch(void* const* d_in, const int* in_sizes, int n_in,
                              void* d_out, int out_size, void* d_ws, size_t ws_size,
                              hipStream_t stream) {
  const float* hs  = (const float*)d_in[0];
  const float* kvs = (const float*)d_in[1];
  const float* Wq  = (const float*)d_in[2];
  const float* bq  = (const float*)d_in[3];
  const float* Wk  = (const float*)d_in[4];
  const float* bk  = (const float*)d_in[5];
  const float* Wv  = (const float*)d_in[6];
  const float* bv  = (const float*)d_in[7];
  const float* kvw = (const float*)d_in[8];
  float* out = (float*)d_out;

  char* w = (char*)d_ws;
  unsigned short* hsb  = (unsigned short*)(w);               // 8 MB  hidden bf16
  unsigned short* wb   = (unsigned short*)(w + (8l  << 20)); // 6 MB  Wq|Wk|Wv bf16
  unsigned short* qbuf = (unsigned short*)(w + (14l << 20)); // 8 MB  Q [bh][2048][64]
  unsigned short* kbuf = (unsigned short*)(w + (22l << 20)); // 16 MB K [bh][4096][64]
  unsigned short* vtb  = (unsigned short*)(w + (38l << 20)); // 16 MB V^T [bh][64][4096]
  float* po = (float*)(w + (64l << 20));                     // 32 MB partial O (2 splits x 16MB)
  float* pl = (float*)(w + (128l << 20));                    // 512 KB partial lsum (2 splits)

  const float* kv0 = kvs;
  const float* kv1 = kvs + 4194304;

  prep_convert<<<dim3(11264), dim3(256), 0, stream>>>(hs, Wq, Wk, Wv, kv0, kvw, hsb, wb, kbuf);
  qkv_gemm<<<dim3(256, 3), dim3(256), 0, stream>>>(hsb, wb, bq, bk, bv, qbuf, kbuf, vtb);
  transpose_v<<<dim3(1024), dim3(256), 0, stream>>>(kv1, vtb, kvw);

  if (ws_size >= (129ul << 20)) {
    attn<32, false><<<dim3(8, 32, 2), dim3(256), 0, stream>>>(qbuf, kbuf, vtb, nullptr, po, pl);
    combine2<<<dim3(4096), dim3(256), 0, stream>>>(po, pl, out);
  } else {
    attn<64, true><<<dim3(8, 32, 1), dim3(256), 0, stream>>>(qbuf, kbuf, vtb, out, nullptr, nullptr);
  }
}

// Round 11
// 242.938 us; speedup vs baseline: 1.1668x; 1.1668x over previous
//
#include <hip/hip_runtime.h>
#include <hip/hip_bf16.h>

// B=2 S=2048 HID=1024 NH=16 HD=64 SKV=2048 L=4096
// d_in: 0 hidden, 1 kvs, 2 Wq, 3 bq, 4 Wk, 5 bk, 6 Wv, 7 bv, 8 kv_weight

typedef __bf16 bf16x8 __attribute__((ext_vector_type(8)));
typedef __bf16 bf16x2 __attribute__((ext_vector_type(2)));
typedef float f32x2 __attribute__((ext_vector_type(2)));
typedef float f32x4 __attribute__((ext_vector_type(4)));
typedef float f32x16 __attribute__((ext_vector_type(16)));
typedef unsigned int uint4v __attribute__((ext_vector_type(4)));
typedef unsigned short u16x4 __attribute__((ext_vector_type(4)));

#define QSCALE 0.0225421100138900525f  // (1/64) * log2(e): folds both HD^-0.5 scales + exp->exp2

static __device__ __forceinline__ unsigned short bf16b(float f) {
  return __builtin_bit_cast(unsigned short, __float2bfloat16(f));
}
// packed f32x2 -> bf16x2 via vector fptrunc: lowers to v_cvt_pk_bf16_f32 (1 op),
// vs __float2bfloat16's potential SW round sequence. Same RNE rounding.
static __device__ __forceinline__ unsigned pk2(float lo, float hi) {
  f32x2 v = { lo, hi };
  bf16x2 b = __builtin_convertvector(v, bf16x2);
  return __builtin_bit_cast(unsigned, b);
}
static __device__ __forceinline__ bf16x8 ld16s(const unsigned short* p) {
  return __builtin_bit_cast(bf16x8, *(const uint4v*)p);
}
static __device__ __forceinline__ float fexp2(float x) {
  float r; asm("v_exp_f32 %0, %1" : "=v"(r) : "v"(x)); return r;
}

typedef __attribute__((address_space(1))) const void gas_void;
typedef __attribute__((address_space(3))) void las_void;
static __device__ __forceinline__ void gload_lds16(const void* g, void* l) {
  __builtin_amdgcn_global_load_lds((gas_void*)g, (las_void*)l, 16, 0, 0);
}

// ---------------- prep: f32->bf16 conversions + kvs[0] -> K buffer ----------------
__global__ __launch_bounds__(256) void prep_convert(
    const float* __restrict__ hs, const float* __restrict__ wq,
    const float* __restrict__ wk, const float* __restrict__ wv,
    const float* __restrict__ kv0, const float* __restrict__ kvw,
    unsigned short* __restrict__ hsb, unsigned short* __restrict__ wb,
    unsigned short* __restrict__ kbuf) {
  long i = ((long)blockIdx.x * 256 + threadIdx.x) * 4;
  const float* src; unsigned short* dst; float s = 1.0f;
  if (i < 4194304)      { src = hs + i;           dst = hsb + i; }
  else if (i < 5242880) { src = wq + (i-4194304); dst = wb + (i-4194304); }
  else if (i < 6291456) { src = wk + (i-5242880); dst = wb + 1048576 + (i-5242880); }
  else if (i < 7340032) { src = wv + (i-6291456); dst = wb + 2097152 + (i-6291456); }
  else { long j = i - 7340032; s = *kvw;
         long bh = j >> 17, r = j & 131071;           // kvs[0]: [bh][2048][64] -> K rows 0..2047 of [bh][4096][64]
         src = kv0 + j; dst = kbuf + (bh << 18) + r; }
  float4 v = *(const float4*)src;
  u16x4 o = { bf16b(v.x*s), bf16b(v.y*s), bf16b(v.z*s), bf16b(v.w*s) };
  *(u16x4*)dst = o;
}

// ---------------- fused QKV projection GEMM (128x128 tile, BK=32, 4 waves) ----------------
// A = hidden bf16 [4096][1024]; W row-major [out][in] == B^T; y = x@W.T + b
// mode 2 (V) writes V^T [bh][64][4096] directly (cols 2048+s) -- no separate transpose pass.
__global__ __launch_bounds__(256) void qkv_gemm(
    const unsigned short* __restrict__ A, const unsigned short* __restrict__ W,
    const float* __restrict__ bq, const float* __restrict__ bk, const float* __restrict__ bv,
    unsigned short* __restrict__ qb, unsigned short* __restrict__ kbuf,
    unsigned short* __restrict__ vtb) {
  int mode = blockIdx.y;
  const unsigned short* Wm = W + mode * 1048576;
  const float* bias = (mode == 0) ? bq : ((mode == 1) ? bk : bv);
  int mt = blockIdx.x >> 3, nt = blockIdx.x & 7;
  int m0 = mt << 7, n0 = nt << 7;
  int wid = threadIdx.x >> 6, ln = threadIdx.x & 63;
  int wr = wid >> 1, wc = wid & 1;
  __shared__ unsigned short As[2][4096], Bs[2][4096];

  f32x4 acc[4][4] = {};

  auto stage = [&](int bb, int kt) {
    #pragma unroll
    for (int i = 0; i < 2; ++i) {
      int c = i*256 + wid*64 + ln;   // chunk16 id 0..511
      int row = c >> 2, sl = c & 3;  // 128 rows x 4 x 16B
      int lb = (i*256 + wid*64) * 8; // wave-uniform LDS base (elems)
      gload_lds16(A  + (long)(m0 + row)*1024 + kt*32 + sl*8, &As[bb][lb]);
      gload_lds16(Wm + (long)(n0 + row)*1024 + kt*32 + sl*8, &Bs[bb][lb]);
    }
  };

  stage(0, 0);
  __syncthreads();
  int buf = 0;
  for (int kt = 0; kt < 32; ++kt) {
    if (kt < 31) stage(buf ^ 1, kt + 1);
    bf16x8 a[4], b[4];
    int rsel = (ln & 15), ksel = (ln >> 4) * 8;
    #pragma unroll
    for (int x = 0; x < 4; ++x) {
      a[x] = ld16s(&As[buf][(wr*64 + x*16 + rsel)*32 + ksel]);
      b[x] = ld16s(&Bs[buf][(wc*64 + x*16 + rsel)*32 + ksel]);
    }
    __builtin_amdgcn_s_setprio(1);
    #pragma unroll
    for (int x = 0; x < 4; ++x)
      #pragma unroll
      for (int y = 0; y < 4; ++y)
        acc[x][y] = __builtin_amdgcn_mfma_f32_16x16x32_bf16(a[x], b[y], acc[x][y], 0, 0, 0);
    __builtin_amdgcn_s_setprio(0);
    __syncthreads();
    buf ^= 1;
  }

  float bias4[4];
  #pragma unroll
  for (int y = 0; y < 4; ++y) bias4[y] = bias[n0 + wc*64 + y*16 + (ln & 15)];

  if (mode == 2) {
    // write V^T: 4 consecutive s at fixed (bh, d) -> contiguous 8B
    #pragma unroll
    for (int x = 0; x < 4; ++x)
      #pragma unroll
      for (int y = 0; y < 4; ++y) {
        int gm = m0 + wr*64 + x*16 + (ln >> 4)*4;       // s-run start (4 consecutive)
        int gn = n0 + wc*64 + y*16 + (ln & 15);
        int bb = gm >> 11, s = gm & 2047, h = gn >> 6, d = gn & 63;
        long bh = bb*16 + h;
        u16x4 o = { bf16b(acc[x][y][0] + bias4[y]), bf16b(acc[x][y][1] + bias4[y]),
                    bf16b(acc[x][y][2] + bias4[y]), bf16b(acc[x][y][3] + bias4[y]) };
        *(u16x4*)(vtb + bh*262144 + (long)d*4096 + 2048 + s) = o;
      }
  } else {
    #pragma unroll
    for (int x = 0; x < 4; ++x)
      #pragma unroll
      for (int y = 0; y < 4; ++y)
        #pragma unroll
        for (int r = 0; r < 4; ++r) {
          int gm = m0 + wr*64 + x*16 + (ln >> 4)*4 + r;   // C/D: col=l&15, row=(l>>4)*4+r
          int gn = n0 + wc*64 + y*16 + (ln & 15);
          float v = acc[x][y][r] + bias4[y];
          int bb = gm >> 11, s = gm & 2047, h = gn >> 6, d = gn & 63;
          long bh = bb*16 + h;
          if (mode == 0) qb[(bh*2048 + s)*64 + d]          = bf16b(v * QSCALE);
          else           kbuf[(bh*4096 + 2048 + s)*64 + d] = bf16b(v);
        }
  }
}

// ---------------- transpose kvs[1] f32 [bh][s][64] -> V^T [bh][64][4096] cols 0..2047 ----------------
__global__ __launch_bounds__(256) void transpose_v(
    const float* __restrict__ src, unsigned short* __restrict__ dst,
    const float* __restrict__ scale_ptr) {
  __shared__ float tile[64 * 65];
  int bh = blockIdx.x >> 5;
  int s0 = (blockIdx.x & 31) << 6;
  int tid = threadIdx.x;
  float sc = *scale_ptr;
  long sb = ((long)bh*2048 + s0) * 64;
  #pragma unroll
  for (int j = 0; j < 4; ++j) {
    int c = tid + j*256;
    int row = c >> 4, sl = c & 15;
    float4 v = *(const float4*)(src + sb + row*64 + sl*4);
    float* p = &tile[row*65 + sl*4];
    p[0] = v.x*sc; p[1] = v.y*sc; p[2] = v.z*sc; p[3] = v.w*sc;
  }
  __syncthreads();
  int d = tid >> 2, kc = tid & 3;
  unsigned short u16[16];
  #pragma unroll
  for (int t = 0; t < 16; ++t) u16[t] = bf16b(tile[(kc*16 + t)*65 + d]);
  uint4v o0v = { (unsigned)u16[0] | ((unsigned)u16[1]<<16), (unsigned)u16[2] | ((unsigned)u16[3]<<16),
                 (unsigned)u16[4] | ((unsigned)u16[5]<<16), (unsigned)u16[6] | ((unsigned)u16[7]<<16) };
  uint4v o1v = { (unsigned)u16[8] | ((unsigned)u16[9]<<16), (unsigned)u16[10] | ((unsigned)u16[11]<<16),
                 (unsigned)u16[12] | ((unsigned)u16[13]<<16), (unsigned)u16[14] | ((unsigned)u16[15]<<16) };
  long db = (long)bh*262144 + (long)d*4096 + s0 + kc*16;
  *(uint4v*)(dst + db) = o0v;
  *(uint4v*)(dst + db + 8) = o1v;
}

// ---------------- flash attention: swapped S^T/O^T layout, 64 queries/wave ----------------
// No max tracking: Q pre-scaled so |scores| << 20; exp2 direct is exact-safe in f32.
// Block = 256 queries (4 waves x 64q in 2 groups of 32). K-frags and V-frags are
// loaded once per cc/ks and shared across both query groups. LDS-staged K/V
// (round-10 lesson: L2-direct exposes ~200cyc latency per MFMA chain, -20%).
template <int NT, bool DIRECT>
__global__ __launch_bounds__(256) void attn(
    const unsigned short* __restrict__ qb, const unsigned short* __restrict__ kb,
    const unsigned short* __restrict__ vtb, float* __restrict__ out,
    float* __restrict__ po, float* __restrict__ pl) {
  int tilei = blockIdx.x, bh = blockIdx.y, sp = blockIdx.z;
  int keyoff = sp * NT * 64;
  int wid = threadIdx.x >> 6, ln = threadIdx.x & 63;
  int lo = ln & 31, hi = ln >> 5;
  __shared__ unsigned short Ks[2][4096], Vs[2][4096]; // K:[64key][64d], V:[64d][64key], 16B-slot swizzled

  const unsigned short* kg = kb  + (long)bh * 262144;
  const unsigned short* vg = vtb + (long)bh * 262144;
  int qbase = tilei*256 + wid*64;
  bf16x8 qf[2][4];
  #pragma unroll
  for (int g = 0; g < 2; ++g) {
    const unsigned short* qrow = qb + ((long)bh*2048 + qbase + g*32 + lo) * 64;
    #pragma unroll
    for (int ds = 0; ds < 4; ++ds) qf[g][ds] = ld16s(qrow + ds*16 + hi*8); // B-frag: col=q, k=8*hi+j
  }

  f32x16 o[2][2] = {};   // [group][dh]
  f32x4 lacc[2] = {};

  auto stage = [&](int bb, int t) {
    int key0 = keyoff + (t << 6);
    #pragma unroll
    for (int i = 0; i < 2; ++i) {
      int c = i*256 + wid*64 + ln;
      int row = c >> 3, sl = c & 7;
      int swz = (sl ^ (row & 7)) * 8;       // pre-swizzled global source, linear LDS dest
      int lb = (i*256 + wid*64) * 8;
      gload_lds16(kg + (long)(key0 + row)*64 + swz, &Ks[bb][lb]);
      gload_lds16(vg + (long)row*4096 + key0 + swz, &Vs[bb][lb]);
    }
  };

  stage(0, 0);
  __syncthreads();
  int buf = 0;
  for (int t = 0; t < NT; ++t) {
    if (t < NT-1) stage(buf ^ 1, t + 1);
    const unsigned short* Kt = Ks[buf];
    const unsigned short* Vt = Vs[buf];
    #pragma unroll
    for (int cc = 0; cc < 2; ++cc) {
      int key = cc*32 + lo;
      bf16x8 kf[4];
      #pragma unroll
      for (int ds = 0; ds < 4; ++ds)
        kf[ds] = ld16s(&Kt[key*64 + ((2*ds + hi) ^ (key & 7))*8]);
      bf16x8 pf[2][2];
      #pragma unroll
      for (int g = 0; g < 2; ++g) {
        // S^T = K . Q^T : lane owns query (qbase+g*32+lo), keys (r&3)+8*(r>>2)+4*hi
        f32x16 st = {};
        __builtin_amdgcn_s_setprio(1);
        #pragma unroll
        for (int ds = 0; ds < 4; ++ds)
          st = __builtin_amdgcn_mfma_f32_32x32x16_bf16(kf[ds], qf[g][ds], st, 0, 0, 0);
        __builtin_amdgcn_s_setprio(0);
        float p[16];
        #pragma unroll
        for (int r = 0; r < 16; ++r) p[r] = fexp2(st[r]);
        f32x4 l4 = { (p[0]+p[1]) + (p[2]+p[3]),   (p[4]+p[5]) + (p[6]+p[7]),
                     (p[8]+p[9]) + (p[10]+p[11]), (p[12]+p[13]) + (p[14]+p[15]) };
        lacc[g] += l4;
        // P^T B-frags via packed cvt (v_cvt_pk_bf16_f32) + permlane32_swap (T12)
        #pragma unroll
        for (int ks = 0; ks < 2; ++ks) {
          unsigned X  = pk2(p[8*ks+0], p[8*ks+1]);
          unsigned X2 = pk2(p[8*ks+2], p[8*ks+3]);
          unsigned Y  = pk2(p[8*ks+4], p[8*ks+5]);
          unsigned Y2 = pk2(p[8*ks+6], p[8*ks+7]);
          asm("v_permlane32_swap_b32 %0, %1" : "+v"(X), "+v"(Y));
          asm("v_permlane32_swap_b32 %0, %1" : "+v"(X2), "+v"(Y2));
          uint4v pw = { X, X2, Y, Y2 };
          pf[g][ks] = __builtin_bit_cast(bf16x8, pw);
        }
      }
      // O^T += V^T . P^T — V-frags shared by both query groups
      #pragma unroll
      for (int ks = 0; ks < 2; ++ks) {
        int slv = ((cc*4 + 2*ks + hi) ^ (lo & 7)) * 8;
        bf16x8 vf0 = ld16s(&Vt[lo*64 + slv]);
        bf16x8 vf1 = ld16s(&Vt[(32 + lo)*64 + slv]);
        __builtin_amdgcn_s_setprio(1);
        #pragma unroll
        for (int g = 0; g < 2; ++g) {
          o[g][0] = __builtin_amdgcn_mfma_f32_32x32x16_bf16(vf0, pf[g][ks], o[g][0], 0, 0, 0);
          o[g][1] = __builtin_amdgcn_mfma_f32_32x32x16_bf16(vf1, pf[g][ks], o[g][1], 0, 0, 0);
        }
        __builtin_amdgcn_s_setprio(0);
      }
    }
    __syncthreads();
    buf ^= 1;
  }

  #pragma unroll
  for (int g = 0; g < 2; ++g) {
    float lsum = (lacc[g][0] + lacc[g][1]) + (lacc[g][2] + lacc[g][3]);
    lsum += __shfl_xor(lsum, 32, 64);
    int q = qbase + g*32 + lo;
    if constexpr (DIRECT) {
      float inv = 1.0f / lsum;
      int bb = bh >> 4, h = bh & 15;
      float* orow = out + ((long)bb*2048 + q)*1024 + h*64;
      #pragma unroll
      for (int dh = 0; dh < 2; ++dh) {
        #pragma unroll
        for (int gg = 0; gg < 4; ++gg) {
          f32x4 vv = { o[g][dh][4*gg]*inv, o[g][dh][4*gg+1]*inv,
                       o[g][dh][4*gg+2]*inv, o[g][dh][4*gg+3]*inv };
          *(f32x4*)(orow + dh*32 + gg*8 + 4*hi) = vv;   // d = (r&3)+8*(r>>2)+4*hi (+32*dh)
        }
      }
    } else {
      float* prow = po + (((long)sp*32 + bh)*2048 + q) * 64;
      #pragma unroll
      for (int dh = 0; dh < 2; ++dh) {
        #pragma unroll
        for (int gg = 0; gg < 4; ++gg) {
          f32x4 vv = { o[g][dh][4*gg], o[g][dh][4*gg+1], o[g][dh][4*gg+2], o[g][dh][4*gg+3] };
          *(f32x4*)(prow + dh*32 + gg*8 + 4*hi) = vv;
        }
      }
      if (hi == 0) pl[((long)sp*32 + bh)*2048 + q] = lsum;
    }
  }
}

// ---------------- combine 2 key-split partials: out = (O0+O1)/(l0+l1) ----------------
__global__ __launch_bounds__(256) void combine2(
    const float* __restrict__ po, const float* __restrict__ pl, float* __restrict__ out) {
  long flat = ((long)blockIdx.x * 256 + threadIdx.x) * 4;   // over 32*2048*64
  int bh = (int)(flat >> 17);
  int rem = (int)(flat & 131071);
  int q = rem >> 6, d = rem & 63;
  f32x4 a = *(const f32x4*)(po + flat);
  f32x4 b = *(const f32x4*)(po + 4194304 + flat);
  float l = pl[bh*2048 + q] + pl[65536 + bh*2048 + q];
  float inv = 1.0f / l;
  f32x4 r = { (a[0]+b[0])*inv, (a[1]+b[1])*inv, (a[2]+b[2])*inv, (a[3]+b[3])*inv };
  *(f32x4*)(out + ((long)(bh >> 4)*2048 + q)*1024 + (bh & 15)*64 + d) = r;
}

extern "C" void kernel_launch(void* const* d_in, const int* in_sizes, int n_in,
                              void* d_out, int out_size, void* d_ws, size_t ws_size,
                              hipStream_t stream) {
  const float* hs  = (const float*)d_in[0];
  const float* kvs = (const float*)d_in[1];
  const float* Wq  = (const float*)d_in[2];
  const float* bq  = (const float*)d_in[3];
  const float* Wk  = (const float*)d_in[4];
  const float* bk  = (const float*)d_in[5];
  const float* Wv  = (const float*)d_in[6];
  const float* bv  = (const float*)d_in[7];
  const float* kvw = (const float*)d_in[8];
  float* out = (float*)d_out;

  char* w = (char*)d_ws;
  unsigned short* hsb  = (unsigned short*)(w);               // 8 MB  hidden bf16
  unsigned short* wb   = (unsigned short*)(w + (8l  << 20)); // 6 MB  Wq|Wk|Wv bf16
  unsigned short* qbuf = (unsigned short*)(w + (14l << 20)); // 8 MB  Q [bh][2048][64]
  unsigned short* kbuf = (unsigned short*)(w + (22l << 20)); // 16 MB K [bh][4096][64]
  unsigned short* vtb  = (unsigned short*)(w + (38l << 20)); // 16 MB V^T [bh][64][4096]
  float* po = (float*)(w + (64l << 20));                     // 32 MB partial O (2 splits x 16MB)
  float* pl = (float*)(w + (128l << 20));                    // 512 KB partial lsum (2 splits)

  const float* kv0 = kvs;
  const float* kv1 = kvs + 4194304;

  prep_convert<<<dim3(11264), dim3(256), 0, stream>>>(hs, Wq, Wk, Wv, kv0, kvw, hsb, wb, kbuf);
  qkv_gemm<<<dim3(256, 3), dim3(256), 0, stream>>>(hsb, wb, bq, bk, bv, qbuf, kbuf, vtb);
  transpose_v<<<dim3(1024), dim3(256), 0, stream>>>(kv1, vtb, kvw);

  if (ws_size >= (129ul << 20)) {
    attn<32, false><<<dim3(8, 32, 2), dim3(256), 0, stream>>>(qbuf, kbuf, vtb, nullptr, po, pl);
    combine2<<<dim3(4096), dim3(256), 0, stream>>>(po, pl, out);
  } else {
    attn<64, true><<<dim3(8, 32, 1), dim3(256), 0, stream>>>(qbuf, kbuf, vtb, out, nullptr, nullptr);
  }
}